// Round 1
// baseline (430.102 us; speedup 1.0000x reference)
//
#include <hip/hip_runtime.h>

// DepthToSpace DCR, block_size=2.
// in:  (16, 256, 128, 128) f32
// out: (16,  64, 256, 256) f32
// out[b, c, 2h+j, 2w+r] = in[b, (2j+r)*64 + c, h, w]
//
// Each thread: 4 consecutive w positions -> reads float4 from each of the two
// source channel rows (r=0, r=1), writes 8 consecutive output floats as two
// interleaved float4 stores. Fully coalesced both directions.

constexpr int B  = 16;
constexpr int D  = 256;
constexpr int H  = 128;
constexpr int W  = 128;
constexpr int BS = 2;
constexpr int C  = D / (BS * BS);   // 64
constexpr int H2 = H * BS;          // 256
constexpr int W2 = W * BS;          // 256

__global__ __launch_bounds__(256) void d2s_kernel(const float* __restrict__ in,
                                                  float* __restrict__ out) {
    const int tid = blockIdx.x * blockDim.x + threadIdx.x;
    // thread layout: [b][c][ho][w4], w4 in [0,32) selecting 4 input w's
    const int w4    = tid & 31;          // W/4 = 32 groups per row
    const int rest  = tid >> 5;
    const int ho    = rest & (H2 - 1);   // 256
    const int rest2 = rest >> 8;
    const int c     = rest2 & (C - 1);   // 64
    const int b     = rest2 >> 6;

    const int h = ho >> 1;
    const int j = ho & 1;

    const size_t in0_off = ((size_t)((b * D + (2 * j + 0) * C + c) * H + h)) * W;
    const size_t in1_off = ((size_t)((b * D + (2 * j + 1) * C + c) * H + h)) * W;

    const float4 a = reinterpret_cast<const float4*>(in + in0_off)[w4];
    const float4 v = reinterpret_cast<const float4*>(in + in1_off)[w4];

    const size_t out_off = ((size_t)((b * C + c) * H2 + ho)) * W2;
    float4* o = reinterpret_cast<float4*>(out + out_off) + (w4 << 1);
    o[0] = make_float4(a.x, v.x, a.y, v.y);
    o[1] = make_float4(a.z, v.z, a.w, v.w);
}

extern "C" void kernel_launch(void* const* d_in, const int* in_sizes, int n_in,
                              void* d_out, int out_size, void* d_ws, size_t ws_size,
                              hipStream_t stream) {
    const float* in = (const float*)d_in[0];
    float* out = (float*)d_out;

    // total threads = B*C*H2*(W/4) = 16*64*256*32 = 8,388,608
    const int total_threads = B * C * H2 * (W / 4);
    const int block = 256;
    const int grid = total_threads / block;   // 32768

    d2s_kernel<<<grid, block, 0, stream>>>(in, out);
}